// Round 1
// baseline (2217.131 us; speedup 1.0000x reference)
//
#include <hip/hip_runtime.h>
#include <math.h>

// ---------------------------------------------------------------------------
// WassersteinLoss: pred = softmax(x, axis=1)[:,1] = sigmoid(x1-x0)  [B,H,W]
// loss = mean_b mean_i (sort(pred_b)[i] - sort(tgt_b)[i])^2
//
// Exact sort via MSD value-bucketing (both dists ~uniform on [0,1), max
// density ~1.13) + per-bucket bitonic sort in LDS. No stability needed.
// ---------------------------------------------------------------------------

namespace {
constexpr int kB    = 16;
constexpr int kN    = 768 * 768;       // 589824 elements per segment
constexpr int kNB   = 8192;            // value buckets per segment (mean occ ~72)
constexpr int kNSeg = 32;              // 16 pred + 16 target segments
constexpr int kTotal = kB * kN;        // 9,437,184

// d_ws layout (bytes)
constexpr size_t CNT_OFF = 0;                                  // u32[32*8192] = 1 MiB
constexpr size_t CUR_OFF = (size_t)kNSeg * kNB * 4;            // u32[32*8192] = 1 MiB
constexpr size_t ACC_OFF = CUR_OFF + (size_t)kNSeg * kNB * 4;  // double
constexpr size_t OFF_OFF = ACC_OFF + 4096;                     // u32[32*8192] = 1 MiB
constexpr size_t KP_OFF  = OFF_OFF + (size_t)kNSeg * kNB * 4;  // float[16*N]
constexpr size_t KT_OFF  = KP_OFF + (size_t)kB * kN * 4;       // float[16*N]
constexpr size_t ZERO_BYTES = ACC_OFF + 8;                     // cnt + cur + acc
}

__device__ __forceinline__ int bucket_of(float v) {
    int b = (int)(v * (float)kNB);
    if (b > kNB - 1) b = kNB - 1;
    if (b < 0) b = 0;
    return b;
}

// Read x, compute pred=sigmoid(x1-x0), store it (linear), histogram buckets.
__global__ void count_pred_kernel(const float* __restrict__ x,
                                  float* __restrict__ pred_out,
                                  unsigned* __restrict__ cnt) {
    int stride = gridDim.x * blockDim.x;
    for (int i = blockIdx.x * blockDim.x + threadIdx.x; i < kTotal; i += stride) {
        int b   = i / kN;
        int idx = i - b * kN;
        float x0 = x[(size_t)b * 2 * kN + idx];
        float x1 = x[(size_t)b * 2 * kN + kN + idx];
        float p  = 1.0f / (1.0f + expf(x0 - x1));
        pred_out[i] = p;
        atomicAdd(&cnt[b * kNB + bucket_of(p)], 1u);
    }
}

__global__ void count_tgt_kernel(const float* __restrict__ t,
                                 unsigned* __restrict__ cnt) {
    int stride = gridDim.x * blockDim.x;
    for (int i = blockIdx.x * blockDim.x + threadIdx.x; i < kTotal; i += stride) {
        int b = i / kN;
        atomicAdd(&cnt[(kB + b) * kNB + bucket_of(t[i])], 1u);
    }
}

// Per-segment exclusive scan over kNB=8192 bucket counts. One block/segment.
__global__ __launch_bounds__(1024) void scan_kernel(const unsigned* __restrict__ cnt,
                                                    unsigned* __restrict__ off) {
    int s = blockIdx.x;
    int t = threadIdx.x;
    __shared__ unsigned sh[1024];
    __shared__ unsigned carry;
    if (t == 0) carry = 0;
    __syncthreads();
    for (int c = 0; c < kNB / 1024; ++c) {
        unsigned v = cnt[s * kNB + c * 1024 + t];
        sh[t] = v;
        __syncthreads();
        for (int d = 1; d < 1024; d <<= 1) {
            unsigned u = (t >= d) ? sh[t - d] : 0u;
            __syncthreads();
            sh[t] += u;
            __syncthreads();
        }
        unsigned incl = sh[t];
        unsigned base = carry;
        off[s * kNB + c * 1024 + t] = base + incl - v;
        __syncthreads();
        if (t == 1023) carry = base + incl;
        __syncthreads();
    }
}

// Scatter pred (read back stored values -> bit-identical buckets) into dstP.
__global__ void scat_pred_kernel(const float* __restrict__ pred_in,
                                 const unsigned* __restrict__ off,
                                 unsigned* __restrict__ cur,
                                 float* __restrict__ dstP) {
    int stride = gridDim.x * blockDim.x;
    for (int i = blockIdx.x * blockDim.x + threadIdx.x; i < kTotal; i += stride) {
        int b = i / kN;
        float p = pred_in[i];
        int bk = b * kNB + bucket_of(p);
        unsigned r = atomicAdd(&cur[bk], 1u);
        dstP[(size_t)b * kN + off[bk] + r] = p;
    }
}

__global__ void scat_tgt_kernel(const float* __restrict__ t,
                                const unsigned* __restrict__ off,
                                unsigned* __restrict__ cur,
                                float* __restrict__ dstT) {
    int stride = gridDim.x * blockDim.x;
    for (int i = blockIdx.x * blockDim.x + threadIdx.x; i < kTotal; i += stride) {
        int b = i / kN;
        float v = t[i];
        int bk = (kB + b) * kNB + bucket_of(v);
        unsigned r = atomicAdd(&cur[bk], 1u);
        dstT[(size_t)b * kN + off[bk] + r] = v;
    }
}

// One 64-thread block per bucket; bitonic sort in LDS (cap 1024, mean n~72).
#define SORT_CAP 1024
__global__ __launch_bounds__(64) void sort_kernel(float* __restrict__ predBuf,
                                                  float* __restrict__ tgtBuf,
                                                  const unsigned* __restrict__ cnt,
                                                  const unsigned* __restrict__ off) {
    int bkt = blockIdx.x;
    int s   = blockIdx.y;                 // 0..31
    unsigned n = cnt[s * kNB + bkt];
    if (n <= 1) return;
    unsigned o = off[s * kNB + bkt];
    float* base = (s < kB ? predBuf + (size_t)s * kN
                          : tgtBuf + (size_t)(s - kB) * kN) + o;
    int t = threadIdx.x;

    if (n > SORT_CAP) {  // statistically impossible safety net: odd-even in gmem
        for (unsigned pass = 0; pass < n; ++pass) {
            for (unsigned i = 2 * t + (pass & 1); i + 1 < n; i += 128) {
                float a = base[i], c = base[i + 1];
                if (a > c) { base[i] = c; base[i + 1] = a; }
            }
            __syncthreads();
        }
        return;
    }

    __shared__ float buf[SORT_CAP];
    unsigned m = 2; while (m < n) m <<= 1;
    for (unsigned i = t; i < m; i += 64)
        buf[i] = (i < n) ? base[i] : __int_as_float(0x7f800000); // +inf pad
    __syncthreads();
    for (unsigned k = 2; k <= m; k <<= 1) {
        for (unsigned j = k >> 1; j > 0; j >>= 1) {
            for (unsigned i = t; i < m; i += 64) {
                unsigned ix = i ^ j;
                if (ix > i) {
                    float a = buf[i], c = buf[ix];
                    bool up = ((i & k) == 0);
                    if ((a > c) == up) { buf[i] = c; buf[ix] = a; }
                }
            }
            __syncthreads();
        }
    }
    for (unsigned i = t; i < n; i += 64) base[i] = buf[i];
}

__global__ void reduce_kernel(const float* __restrict__ sp,
                              const float* __restrict__ sq,
                              double* __restrict__ acc) {
    size_t stride = (size_t)gridDim.x * blockDim.x;
    double s = 0.0;
    for (size_t i = (size_t)blockIdx.x * blockDim.x + threadIdx.x; i < (size_t)kTotal; i += stride) {
        float d = sp[i] - sq[i];
        s += (double)d * (double)d;
    }
    for (int o = 32; o > 0; o >>= 1) s += __shfl_down(s, o, 64);
    __shared__ double sh[4];
    int lane = threadIdx.x & 63, w = threadIdx.x >> 6;
    if (lane == 0) sh[w] = s;
    __syncthreads();
    if (threadIdx.x == 0) atomicAdd(acc, sh[0] + sh[1] + sh[2] + sh[3]);
}

__global__ void fin_kernel(const double* __restrict__ acc, float* __restrict__ out) {
    out[0] = (float)(acc[0] / ((double)kB * (double)kN));
}

extern "C" void kernel_launch(void* const* d_in, const int* in_sizes, int n_in,
                              void* d_out, int out_size, void* d_ws, size_t ws_size,
                              hipStream_t stream) {
    const float* x = (const float*)d_in[0];   // [16,2,768,768]
    const float* t = (const float*)d_in[1];   // [16,768,768]
    float* out = (float*)d_out;

    char* ws = (char*)d_ws;
    unsigned* cnt = (unsigned*)(ws + CNT_OFF);
    unsigned* cur = (unsigned*)(ws + CUR_OFF);
    double*   acc = (double*)  (ws + ACC_OFF);
    unsigned* off = (unsigned*)(ws + OFF_OFF);
    float*    kp  = (float*)   (ws + KP_OFF);  // unsorted pred, then sorted target
    float*    kt  = (float*)   (ws + KT_OFF);  // bucketed/sorted pred

    hipMemsetAsync(ws, 0, ZERO_BYTES, stream);

    const int thr = 256;
    count_pred_kernel<<<4096, thr, 0, stream>>>(x, kp, cnt);
    count_tgt_kernel <<<4096, thr, 0, stream>>>(t, cnt);
    scan_kernel      <<<kNSeg, 1024, 0, stream>>>(cnt, off);
    scat_pred_kernel <<<4096, thr, 0, stream>>>(kp, off, cur, kt);  // pred -> kt
    scat_tgt_kernel  <<<4096, thr, 0, stream>>>(t,  off, cur, kp);  // tgt  -> kp
    sort_kernel<<<dim3(kNB, kNSeg), 64, 0, stream>>>(kt, kp, cnt, off);
    reduce_kernel<<<2048, thr, 0, stream>>>(kt, kp, acc);
    fin_kernel<<<1, 1, 0, stream>>>(acc, out);
}

// Round 2
// 1003.919 us; speedup vs baseline: 2.2085x; 2.2085x over previous
//
#include <hip/hip_runtime.h>
#include <math.h>

// ---------------------------------------------------------------------------
// WassersteinLoss: pred = sigmoid(x1-x0); loss = mean_b mean_i
// (sort(pred_b)[i] - sort(tgt_b)[i])^2.
// Two-level exact sort: 256 coarse value-buckets/segment (block-local LDS
// counting-sort scatter -> coalesced writes), then per-bucket kernel does a
// 64-way fine split in LDS + per-wave bitonic subsorts. Pow2 bucket scales
// (256, 16384) make bucket functions exactly consistent across kernels.
// ---------------------------------------------------------------------------

namespace {
constexpr int kB     = 16;
constexpr int kN     = 768 * 768;     // 589824 per segment
constexpr int kNC    = 256;           // coarse buckets per segment
constexpr int kNSub  = 64;            // fine subs per coarse bucket
constexpr int kSubCap = 128;          // sub capacity (mean ~40, max ~70)
constexpr int kNSeg  = 32;            // 16 pred + 16 target
constexpr int kChunk = 8192;          // elements per scatter block
constexpr int kBlksPerSeg = kN / kChunk;  // 72

// d_ws layout
constexpr size_t CNT_OFF  = 0;                              // u32[32*256]
constexpr size_t CUR_OFF  = CNT_OFF + (size_t)kNSeg*kNC*4;  // u32[32*256]
constexpr size_t ACC_OFF  = CUR_OFF + (size_t)kNSeg*kNC*4;  // double
constexpr size_t OFF_OFF  = ACC_OFF + 256;                  // u32[32*256]
constexpr size_t BUFP_OFF = 1 << 20;                        // float[16*N]
constexpr size_t BUFT_OFF = BUFP_OFF + (size_t)kB*kN*4;     // float[16*N]
constexpr size_t ZERO_BYTES = ACC_OFF + 8;
}

__device__ __forceinline__ float pred_of(float x0, float x1) {
    return 1.0f / (1.0f + expf(x0 - x1));
}
__device__ __forceinline__ int bucket_c(float v) {
    int b = (int)(v * 256.0f);                // exact pow2 multiply
    return b < 0 ? 0 : (b > kNC - 1 ? kNC - 1 : b);
}

// ---- count: coarse histograms for pred & target, LDS-staged --------------
__global__ __launch_bounds__(256) void count_kernel(const float4* __restrict__ x,
                                                    const float4* __restrict__ t,
                                                    unsigned* __restrict__ cnt) {
    int s = blockIdx.y, c = blockIdx.x, tid = threadIdx.x;
    __shared__ unsigned h[2 * kNC];
    for (int i = tid; i < 2 * kNC; i += 256) h[i] = 0;
    __syncthreads();
    const int q4 = kN / 4, c4 = kChunk / 4;
    const float4* x0p = x + (size_t)s * 2 * q4 + (size_t)c * c4;
    const float4* x1p = x0p + q4;
    const float4* tp  = t + (size_t)s * q4 + (size_t)c * c4;
    for (int k = tid; k < c4; k += 256) {
        float4 a = x0p[k], b = x1p[k], tv = tp[k];
        atomicAdd(&h[bucket_c(pred_of(a.x, b.x))], 1u);
        atomicAdd(&h[bucket_c(pred_of(a.y, b.y))], 1u);
        atomicAdd(&h[bucket_c(pred_of(a.z, b.z))], 1u);
        atomicAdd(&h[bucket_c(pred_of(a.w, b.w))], 1u);
        atomicAdd(&h[kNC + bucket_c(tv.x)], 1u);
        atomicAdd(&h[kNC + bucket_c(tv.y)], 1u);
        atomicAdd(&h[kNC + bucket_c(tv.z)], 1u);
        atomicAdd(&h[kNC + bucket_c(tv.w)], 1u);
    }
    __syncthreads();
    for (int i = tid; i < 2 * kNC; i += 256) {
        unsigned v = h[i];
        if (v) atomicAdd(&cnt[((i < kNC) ? s : kB + s) * kNC + (i & (kNC - 1))], v);
    }
}

// ---- per-segment exclusive scan of 256 coarse counts ---------------------
__global__ __launch_bounds__(256) void scan_kernel(const unsigned* __restrict__ cnt,
                                                   unsigned* __restrict__ off) {
    int s = blockIdx.x, tid = threadIdx.x;
    __shared__ unsigned sh[kNC];
    unsigned v = cnt[s * kNC + tid];
    sh[tid] = v; __syncthreads();
    for (int d = 1; d < kNC; d <<= 1) {
        unsigned u = (tid >= d) ? sh[tid - d] : 0u;
        __syncthreads();
        sh[tid] += u;
        __syncthreads();
    }
    off[s * kNC + tid] = sh[tid] - v;
}

// ---- scatter: block-local counting sort in LDS, coalesced global writes --
__global__ __launch_bounds__(256) void scatter_kernel(const float4* __restrict__ x,
                                                      const float4* __restrict__ t,
                                                      const unsigned* __restrict__ off,
                                                      unsigned* __restrict__ gcur,
                                                      float* __restrict__ bufP,
                                                      float* __restrict__ bufT) {
    int s = blockIdx.y, c = blockIdx.x, z = blockIdx.z, tid = threadIdx.x;
    __shared__ float vals[kChunk];                       // 32 KB
    __shared__ unsigned hist[kNC], scn[kNC], gbase[kNC], curs[kNC];
    hist[tid] = 0; curs[tid] = 0;
    __syncthreads();

    const int q4 = kN / 4, c4 = kChunk / 4;              // c4 = 2048
    float4 v[8];
    if (z == 0) {
        const float4* x0p = x + (size_t)s * 2 * q4 + (size_t)c * c4;
        const float4* x1p = x0p + q4;
#pragma unroll
        for (int k = 0; k < 8; ++k) {
            float4 a = x0p[tid + k * 256], b = x1p[tid + k * 256];
            v[k].x = pred_of(a.x, b.x); v[k].y = pred_of(a.y, b.y);
            v[k].z = pred_of(a.z, b.z); v[k].w = pred_of(a.w, b.w);
        }
    } else {
        const float4* tp = t + (size_t)s * q4 + (size_t)c * c4;
#pragma unroll
        for (int k = 0; k < 8; ++k) v[k] = tp[tid + k * 256];
    }
#pragma unroll
    for (int k = 0; k < 8; ++k) {
        atomicAdd(&hist[bucket_c(v[k].x)], 1u);
        atomicAdd(&hist[bucket_c(v[k].y)], 1u);
        atomicAdd(&hist[bucket_c(v[k].z)], 1u);
        atomicAdd(&hist[bucket_c(v[k].w)], 1u);
    }
    __syncthreads();
    // inclusive scan -> exclusive, one bucket per thread (blockDim == kNC)
    unsigned hv = hist[tid];
    scn[tid] = hv; __syncthreads();
    for (int d = 1; d < kNC; d <<= 1) {
        unsigned u = (tid >= d) ? scn[tid - d] : 0u;
        __syncthreads();
        scn[tid] += u;
        __syncthreads();
    }
    unsigned excl = scn[tid] - hv;
    int sb = ((z == 0) ? s : kB + s) * kNC + tid;
    gbase[tid] = off[sb] + (hv ? atomicAdd(&gcur[sb], hv) : 0u);
    __syncthreads();
    scn[tid] = excl;
    __syncthreads();
    // local scatter into LDS (bucket-ordered)
#pragma unroll
    for (int k = 0; k < 8; ++k) {
        float p;
        p = v[k].x; vals[scn[bucket_c(p)] + atomicAdd(&curs[bucket_c(p)], 1u)] = p;
        p = v[k].y; vals[scn[bucket_c(p)] + atomicAdd(&curs[bucket_c(p)], 1u)] = p;
        p = v[k].z; vals[scn[bucket_c(p)] + atomicAdd(&curs[bucket_c(p)], 1u)] = p;
        p = v[k].w; vals[scn[bucket_c(p)] + atomicAdd(&curs[bucket_c(p)], 1u)] = p;
    }
    __syncthreads();
    // coalesced write-out: consecutive i -> consecutive dst within each run
    float* dst = (z == 0) ? (bufP + (size_t)s * kN) : (bufT + (size_t)s * kN);
    for (int i = tid; i < kChunk; i += 256) {
        float val = vals[i];
        int b = bucket_c(val);
        dst[gbase[b] + ((unsigned)i - scn[b])] = val;
    }
}

// ---- sort: fine 64-way split in LDS + per-wave bitonic subsorts ----------
__device__ void fallback_sort(float* base, unsigned n) {  // never expected
    for (unsigned pass = 0; pass < n; ++pass) {
        for (unsigned i = 2 * threadIdx.x + (pass & 1); i + 1 < n; i += 512) {
            float a = base[i], c = base[i + 1];
            if (a > c) { base[i] = c; base[i + 1] = a; }
        }
        __syncthreads();
    }
}

__global__ __launch_bounds__(256) void sort_kernel(float* __restrict__ bufP,
                                                   float* __restrict__ bufT,
                                                   const unsigned* __restrict__ cnt,
                                                   const unsigned* __restrict__ off) {
    int b = blockIdx.x, s = blockIdx.y, tid = threadIdx.x;
    unsigned n = cnt[s * kNC + b];
    if (n == 0) return;
    float* base = ((s < kB) ? bufP + (size_t)s * kN
                            : bufT + (size_t)(s - kB) * kN) + off[s * kNC + b];
    __shared__ float S[kNSub * kSubCap];                  // 32 KB
    __shared__ unsigned sh[kNSub], sscan[kNSub];
    __shared__ int sflag;
    if (tid < kNSub) sh[tid] = 0;
    if (tid == 0) sflag = 0;
    __syncthreads();
    for (unsigned i = tid; i < n; i += 256) {
        float v = base[i];
        int sub = (int)(v * 16384.0f) - (b << 6);         // exact: in [0,64)
        sub = sub < 0 ? 0 : (sub > kNSub - 1 ? kNSub - 1 : sub);
        unsigned r = atomicAdd(&sh[sub], 1u);
        if (r < kSubCap) S[sub * kSubCap + r] = v; else sflag = 1;
    }
    __syncthreads();
    if (sflag) { fallback_sort(base, n); return; }        // block-uniform
    if (tid < kNSub) {                                    // wave 0: excl scan
        unsigned vv = sh[tid], sc = vv;
        for (int d = 1; d < kNSub; d <<= 1) {
            unsigned u = __shfl_up(sc, d, 64);
            if (tid >= d) sc += u;
        }
        sscan[tid] = sc - vv;
    }
    __syncthreads();
    int wave = tid >> 6, lane = tid & 63;
    for (int sub = wave; sub < kNSub; sub += 4) {
        int ns = (int)sh[sub];
        if (ns > 1) {
            int m = 2; while (m < ns) m <<= 1;            // <= 128
            volatile float* P = S + sub * kSubCap;
            for (int i = lane; i < m; i += 64)
                if (i >= ns) P[i] = __int_as_float(0x7f800000);
            __builtin_amdgcn_wave_barrier();
            for (int k = 2; k <= m; k <<= 1) {
                for (int j = k >> 1; j > 0; j >>= 1) {
                    for (int i = lane; i < m; i += 64) {
                        int ix = i ^ j;
                        if (ix > i) {
                            float a = P[i], c2 = P[ix];
                            bool sw = ((i & k) == 0) ? (a > c2) : (a < c2);
                            if (sw) { P[i] = c2; P[ix] = a; }
                        }
                    }
                    __builtin_amdgcn_wave_barrier();
                }
            }
        }
        unsigned o = sscan[sub];
        for (int j = lane; j < ns; j += 64) base[o + j] = S[sub * kSubCap + j];
    }
}

// ---- reduce + finalize ---------------------------------------------------
__global__ void reduce_kernel(const float4* __restrict__ sp,
                              const float4* __restrict__ sq,
                              double* __restrict__ acc) {
    const int total4 = kB * kN / 4;
    int stride = gridDim.x * blockDim.x;
    double ssum = 0.0;
    for (int i = blockIdx.x * blockDim.x + threadIdx.x; i < total4; i += stride) {
        float4 a = sp[i], b = sq[i];
        float d0 = a.x - b.x, d1 = a.y - b.y, d2 = a.z - b.z, d3 = a.w - b.w;
        ssum += (double)d0 * d0 + (double)d1 * d1 + (double)d2 * d2 + (double)d3 * d3;
    }
    for (int o = 32; o > 0; o >>= 1) ssum += __shfl_down(ssum, o, 64);
    __shared__ double shm[4];
    int lane = threadIdx.x & 63, w = threadIdx.x >> 6;
    if (lane == 0) shm[w] = ssum;
    __syncthreads();
    if (threadIdx.x == 0) atomicAdd(acc, shm[0] + shm[1] + shm[2] + shm[3]);
}

__global__ void fin_kernel(const double* __restrict__ acc, float* __restrict__ out) {
    out[0] = (float)(acc[0] / ((double)kB * (double)kN));
}

extern "C" void kernel_launch(void* const* d_in, const int* in_sizes, int n_in,
                              void* d_out, int out_size, void* d_ws, size_t ws_size,
                              hipStream_t stream) {
    const float4* x = (const float4*)d_in[0];   // [16,2,768,768]
    const float4* t = (const float4*)d_in[1];   // [16,768,768]
    float* out = (float*)d_out;

    char* ws = (char*)d_ws;
    unsigned* cnt  = (unsigned*)(ws + CNT_OFF);
    unsigned* gcur = (unsigned*)(ws + CUR_OFF);
    double*   acc  = (double*)  (ws + ACC_OFF);
    unsigned* off  = (unsigned*)(ws + OFF_OFF);
    float*    bufP = (float*)   (ws + BUFP_OFF);
    float*    bufT = (float*)   (ws + BUFT_OFF);

    hipMemsetAsync(ws, 0, ZERO_BYTES, stream);
    count_kernel  <<<dim3(kBlksPerSeg, kB),    256, 0, stream>>>(x, t, cnt);
    scan_kernel   <<<kNSeg,                    256, 0, stream>>>(cnt, off);
    scatter_kernel<<<dim3(kBlksPerSeg, kB, 2), 256, 0, stream>>>(x, t, off, gcur, bufP, bufT);
    sort_kernel   <<<dim3(kNC, kNSeg),         256, 0, stream>>>(bufP, bufT, cnt, off);
    reduce_kernel <<<2048,                     256, 0, stream>>>((const float4*)bufP,
                                                                 (const float4*)bufT, acc);
    fin_kernel    <<<1, 1, 0, stream>>>(acc, out);
}

// Round 3
// 478.054 us; speedup vs baseline: 4.6378x; 2.1000x over previous
//
#include <hip/hip_runtime.h>
#include <math.h>

// ---------------------------------------------------------------------------
// WassersteinLoss: pred = sigmoid(x1-x0); loss = mean_b mean_i
// (sort(pred_b)[i] - sort(tgt_b)[i])^2.
// Two-level exact sort: 256 coarse value-buckets/segment (block-local LDS
// counting-sort scatter -> coalesced writes), then per-bucket kernel splits
// 128-way in LDS and sorts each ~18-elem sub fully in registers with a
// shfl_xor bitonic network (64 elems/wave, +inf pad). Pow2 bucket scales
// (256, 32768) keep bucket functions exactly consistent across kernels.
// ---------------------------------------------------------------------------

namespace {
constexpr int kB     = 16;
constexpr int kN     = 768 * 768;     // 589824 per segment
constexpr int kNC    = 256;           // coarse buckets per segment
constexpr int kNSub  = 128;           // fine subs per coarse bucket
constexpr int kSubCap = 64;           // one wave sorts one sub in registers
constexpr int kNSeg  = 32;            // 16 pred + 16 target
constexpr int kChunk = 8192;          // elements per scatter block
constexpr int kBlksPerSeg = kN / kChunk;  // 72

// d_ws layout
constexpr size_t CNT_OFF  = 0;                              // u32[32*256]
constexpr size_t CUR_OFF  = CNT_OFF + (size_t)kNSeg*kNC*4;  // u32[32*256]
constexpr size_t ACC_OFF  = CUR_OFF + (size_t)kNSeg*kNC*4;  // double
constexpr size_t OFF_OFF  = ACC_OFF + 256;                  // u32[32*256]
constexpr size_t BUFP_OFF = 1 << 20;                        // float[16*N]
constexpr size_t BUFT_OFF = BUFP_OFF + (size_t)kB*kN*4;     // float[16*N]
constexpr size_t ZERO_BYTES = ACC_OFF + 8;
}

__device__ __forceinline__ float pred_of(float x0, float x1) {
    return 1.0f / (1.0f + expf(x0 - x1));
}
__device__ __forceinline__ int bucket_c(float v) {
    int b = (int)(v * 256.0f);                // exact pow2 multiply
    return b < 0 ? 0 : (b > kNC - 1 ? kNC - 1 : b);
}

// ---- count: coarse histograms for pred & target, LDS-staged --------------
__global__ __launch_bounds__(256) void count_kernel(const float4* __restrict__ x,
                                                    const float4* __restrict__ t,
                                                    unsigned* __restrict__ cnt) {
    int s = blockIdx.y, c = blockIdx.x, tid = threadIdx.x;
    __shared__ unsigned h[2 * kNC];
    for (int i = tid; i < 2 * kNC; i += 256) h[i] = 0;
    __syncthreads();
    const int q4 = kN / 4, c4 = kChunk / 4;
    const float4* x0p = x + (size_t)s * 2 * q4 + (size_t)c * c4;
    const float4* x1p = x0p + q4;
    const float4* tp  = t + (size_t)s * q4 + (size_t)c * c4;
    for (int k = tid; k < c4; k += 256) {
        float4 a = x0p[k], b = x1p[k], tv = tp[k];
        atomicAdd(&h[bucket_c(pred_of(a.x, b.x))], 1u);
        atomicAdd(&h[bucket_c(pred_of(a.y, b.y))], 1u);
        atomicAdd(&h[bucket_c(pred_of(a.z, b.z))], 1u);
        atomicAdd(&h[bucket_c(pred_of(a.w, b.w))], 1u);
        atomicAdd(&h[kNC + bucket_c(tv.x)], 1u);
        atomicAdd(&h[kNC + bucket_c(tv.y)], 1u);
        atomicAdd(&h[kNC + bucket_c(tv.z)], 1u);
        atomicAdd(&h[kNC + bucket_c(tv.w)], 1u);
    }
    __syncthreads();
    for (int i = tid; i < 2 * kNC; i += 256) {
        unsigned v = h[i];
        if (v) atomicAdd(&cnt[((i < kNC) ? s : kB + s) * kNC + (i & (kNC - 1))], v);
    }
}

// ---- per-segment exclusive scan of 256 coarse counts ---------------------
__global__ __launch_bounds__(256) void scan_kernel(const unsigned* __restrict__ cnt,
                                                   unsigned* __restrict__ off) {
    int s = blockIdx.x, tid = threadIdx.x;
    __shared__ unsigned sh[kNC];
    unsigned v = cnt[s * kNC + tid];
    sh[tid] = v; __syncthreads();
    for (int d = 1; d < kNC; d <<= 1) {
        unsigned u = (tid >= d) ? sh[tid - d] : 0u;
        __syncthreads();
        sh[tid] += u;
        __syncthreads();
    }
    off[s * kNC + tid] = sh[tid] - v;
}

// ---- scatter: block-local counting sort in LDS, coalesced global writes --
__global__ __launch_bounds__(256) void scatter_kernel(const float4* __restrict__ x,
                                                      const float4* __restrict__ t,
                                                      const unsigned* __restrict__ off,
                                                      unsigned* __restrict__ gcur,
                                                      float* __restrict__ bufP,
                                                      float* __restrict__ bufT) {
    int s = blockIdx.y, c = blockIdx.x, z = blockIdx.z, tid = threadIdx.x;
    __shared__ float vals[kChunk];                       // 32 KB
    __shared__ unsigned hist[kNC], scn[kNC], gbase[kNC], curs[kNC];
    hist[tid] = 0; curs[tid] = 0;
    __syncthreads();

    const int q4 = kN / 4, c4 = kChunk / 4;              // c4 = 2048
    float4 v[8];
    if (z == 0) {
        const float4* x0p = x + (size_t)s * 2 * q4 + (size_t)c * c4;
        const float4* x1p = x0p + q4;
#pragma unroll
        for (int k = 0; k < 8; ++k) {
            float4 a = x0p[tid + k * 256], b = x1p[tid + k * 256];
            v[k].x = pred_of(a.x, b.x); v[k].y = pred_of(a.y, b.y);
            v[k].z = pred_of(a.z, b.z); v[k].w = pred_of(a.w, b.w);
        }
    } else {
        const float4* tp = t + (size_t)s * q4 + (size_t)c * c4;
#pragma unroll
        for (int k = 0; k < 8; ++k) v[k] = tp[tid + k * 256];
    }
#pragma unroll
    for (int k = 0; k < 8; ++k) {
        atomicAdd(&hist[bucket_c(v[k].x)], 1u);
        atomicAdd(&hist[bucket_c(v[k].y)], 1u);
        atomicAdd(&hist[bucket_c(v[k].z)], 1u);
        atomicAdd(&hist[bucket_c(v[k].w)], 1u);
    }
    __syncthreads();
    // inclusive scan -> exclusive, one bucket per thread (blockDim == kNC)
    unsigned hv = hist[tid];
    scn[tid] = hv; __syncthreads();
    for (int d = 1; d < kNC; d <<= 1) {
        unsigned u = (tid >= d) ? scn[tid - d] : 0u;
        __syncthreads();
        scn[tid] += u;
        __syncthreads();
    }
    unsigned excl = scn[tid] - hv;
    int sb = ((z == 0) ? s : kB + s) * kNC + tid;
    gbase[tid] = off[sb] + (hv ? atomicAdd(&gcur[sb], hv) : 0u);
    __syncthreads();
    scn[tid] = excl;
    __syncthreads();
    // local scatter into LDS (bucket-ordered)
#pragma unroll
    for (int k = 0; k < 8; ++k) {
        float p;
        p = v[k].x; vals[scn[bucket_c(p)] + atomicAdd(&curs[bucket_c(p)], 1u)] = p;
        p = v[k].y; vals[scn[bucket_c(p)] + atomicAdd(&curs[bucket_c(p)], 1u)] = p;
        p = v[k].z; vals[scn[bucket_c(p)] + atomicAdd(&curs[bucket_c(p)], 1u)] = p;
        p = v[k].w; vals[scn[bucket_c(p)] + atomicAdd(&curs[bucket_c(p)], 1u)] = p;
    }
    __syncthreads();
    // coalesced write-out: consecutive i -> consecutive dst within each run
    float* dst = (z == 0) ? (bufP + (size_t)s * kN) : (bufT + (size_t)s * kN);
    for (int i = tid; i < kChunk; i += 256) {
        float val = vals[i];
        int b = bucket_c(val);
        dst[gbase[b] + ((unsigned)i - scn[b])] = val;
    }
}

// ---- sort: 128-way fine split in LDS, shfl_xor register bitonic per sub --
__global__ __launch_bounds__(512) void sort_kernel(float* __restrict__ bufP,
                                                   float* __restrict__ bufT,
                                                   const unsigned* __restrict__ cnt,
                                                   const unsigned* __restrict__ off) {
    int b = blockIdx.x, s = blockIdx.y, tid = threadIdx.x;
    unsigned n = cnt[s * kNC + b];
    if (n == 0) return;
    float* base = ((s < kB) ? bufP + (size_t)s * kN
                            : bufT + (size_t)(s - kB) * kN) + off[s * kNC + b];
    __shared__ float S[kNSub * kSubCap];                  // 32 KB (8192 floats)
    __shared__ unsigned scnt[kNSub], sscan[kNSub];
    __shared__ int sflag;
    if (tid < kNSub) scnt[tid] = 0;
    if (tid == 0) sflag = 0;
    __syncthreads();

    // single-pass scatter into fine subs (rank within sub arbitrary)
    for (unsigned i = tid; i < n; i += 512) {
        float v = base[i];
        int sub = (int)(v * 32768.0f) - (b << 7);         // exact: in [0,128)
        sub = sub < 0 ? 0 : (sub > kNSub - 1 ? kNSub - 1 : sub);
        unsigned r = atomicAdd(&scnt[sub], 1u);
        if (r < kSubCap) S[sub * kSubCap + r] = v; else sflag = 1;
    }
    __syncthreads();

    if (sflag) {                                          // ~impossible fallback
        if (n <= 2 * kNSub * kSubCap) {                   // block LDS bitonic
            // NOTE: needs n <= 8192; coarse buckets are ~2300-2900.
            unsigned m = 2; while (m < n) m <<= 1;        // <= 8192
            for (unsigned i = tid; i < m; i += 512)
                S[i] = (i < n) ? base[i] : __int_as_float(0x7f800000);
            __syncthreads();
            for (unsigned k = 2; k <= m; k <<= 1)
                for (unsigned j = k >> 1; j > 0; j >>= 1) {
                    for (unsigned i = tid; i < m; i += 512) {
                        unsigned ix = i ^ j;
                        if (ix > i) {
                            float a = S[i], c2 = S[ix];
                            bool up = ((i & k) == 0);
                            if ((a > c2) == up) { S[i] = c2; S[ix] = a; }
                        }
                    }
                    __syncthreads();
                }
            for (unsigned i = tid; i < n; i += 512) base[i] = S[i];
        } else {                                          // gmem odd-even
            for (unsigned pass = 0; pass < n; ++pass) {
                for (unsigned i = 2 * tid + (pass & 1); i + 1 < n; i += 1024) {
                    float a = base[i], c2 = base[i + 1];
                    if (a > c2) { base[i] = c2; base[i + 1] = a; }
                }
                __syncthreads();
            }
        }
        return;
    }

    // exclusive scan of the 128 sub counts (Hillis-Steele in LDS, 7 steps)
    if (tid < kNSub) sscan[tid] = scnt[tid];
    __syncthreads();
    for (int d = 1; d < kNSub; d <<= 1) {
        unsigned u = (tid < kNSub && tid >= d) ? sscan[tid - d] : 0u;
        __syncthreads();
        if (tid < kNSub) sscan[tid] += u;
        __syncthreads();
    }

    // one sub per wave pass: register bitonic sort of 64 via shfl_xor
    int wave = tid >> 6, lane = tid & 63;
    for (int sub = wave; sub < kNSub; sub += 8) {
        int ns = (int)scnt[sub];
        if (ns == 0) continue;
        float v = (lane < ns) ? S[sub * kSubCap + lane]
                              : __int_as_float(0x7f800000);
        if (ns > 1) {
#pragma unroll
            for (int k = 2; k <= 64; k <<= 1) {
#pragma unroll
                for (int j = k >> 1; j > 0; j >>= 1) {
                    float o = __shfl_xor(v, j, 64);
                    bool up    = ((lane & k) == 0);
                    bool lower = ((lane & j) == 0);
                    v = (up == lower) ? fminf(v, o) : fmaxf(v, o);
                }
            }
        }
        unsigned o = sscan[sub] - scnt[sub];              // exclusive offset
        if (lane < ns) base[o + lane] = v;
    }
}

// ---- reduce + finalize ---------------------------------------------------
__global__ void reduce_kernel(const float4* __restrict__ sp,
                              const float4* __restrict__ sq,
                              double* __restrict__ acc) {
    const int total4 = kB * kN / 4;
    int stride = gridDim.x * blockDim.x;
    double ssum = 0.0;
    for (int i = blockIdx.x * blockDim.x + threadIdx.x; i < total4; i += stride) {
        float4 a = sp[i], b = sq[i];
        float d0 = a.x - b.x, d1 = a.y - b.y, d2 = a.z - b.z, d3 = a.w - b.w;
        ssum += (double)d0 * d0 + (double)d1 * d1 + (double)d2 * d2 + (double)d3 * d3;
    }
    for (int o = 32; o > 0; o >>= 1) ssum += __shfl_down(ssum, o, 64);
    __shared__ double shm[4];
    int lane = threadIdx.x & 63, w = threadIdx.x >> 6;
    if (lane == 0) shm[w] = ssum;
    __syncthreads();
    if (threadIdx.x == 0) atomicAdd(acc, shm[0] + shm[1] + shm[2] + shm[3]);
}

__global__ void fin_kernel(const double* __restrict__ acc, float* __restrict__ out) {
    out[0] = (float)(acc[0] / ((double)kB * (double)kN));
}

extern "C" void kernel_launch(void* const* d_in, const int* in_sizes, int n_in,
                              void* d_out, int out_size, void* d_ws, size_t ws_size,
                              hipStream_t stream) {
    const float4* x = (const float4*)d_in[0];   // [16,2,768,768]
    const float4* t = (const float4*)d_in[1];   // [16,768,768]
    float* out = (float*)d_out;

    char* ws = (char*)d_ws;
    unsigned* cnt  = (unsigned*)(ws + CNT_OFF);
    unsigned* gcur = (unsigned*)(ws + CUR_OFF);
    double*   acc  = (double*)  (ws + ACC_OFF);
    unsigned* off  = (unsigned*)(ws + OFF_OFF);
    float*    bufP = (float*)   (ws + BUFP_OFF);
    float*    bufT = (float*)   (ws + BUFT_OFF);

    hipMemsetAsync(ws, 0, ZERO_BYTES, stream);
    count_kernel  <<<dim3(kBlksPerSeg, kB),    256, 0, stream>>>(x, t, cnt);
    scan_kernel   <<<kNSeg,                    256, 0, stream>>>(cnt, off);
    scatter_kernel<<<dim3(kBlksPerSeg, kB, 2), 256, 0, stream>>>(x, t, off, gcur, bufP, bufT);
    sort_kernel   <<<dim3(kNC, kNSeg),         512, 0, stream>>>(bufP, bufT, cnt, off);
    reduce_kernel <<<2048,                     256, 0, stream>>>((const float4*)bufP,
                                                                 (const float4*)bufT, acc);
    fin_kernel    <<<1, 1, 0, stream>>>(acc, out);
}